// Round 12
// baseline (837.180 us; speedup 1.0000x reference)
//
#include <hip/hip_runtime.h>
#include <math.h>

#define NNODES 100000
#define NEDGES 800000
#define NGRAPH 64
#define NHEAD  4
#define FINALD 512
#define HIDG   64
#define LATD   128
#define K1P    96   // layer-1 K padded (92 -> 96)
#define NB_SCAN 98  // ceil(NNODES/1024)
#define PQ     16   // pool chunks per graph
#define SLOTS  64   // LDS weight slots per node (deg>64 -> fallback recompute)

typedef unsigned int uint;
typedef unsigned short ushort;
typedef __attribute__((ext_vector_type(8))) short bf16x8;
typedef __attribute__((ext_vector_type(4))) float f32x4;

// ---- bf16 helpers ----
__device__ __forceinline__ float bflo(uint u) { return __uint_as_float(u << 16); }
__device__ __forceinline__ float bfhi(uint u) { return __uint_as_float(u & 0xffff0000u); }
__device__ __forceinline__ ushort f2bf(float f) {
    uint u = __float_as_uint(f);
    return (ushort)((u + 0x7fffu + ((u >> 16) & 1u)) >> 16);
}
__device__ __forceinline__ uint pack2(float a, float b) {
    return (uint)f2bf(a) | ((uint)f2bf(b) << 16);
}
__device__ __forceinline__ float selh(float4 v, int h) {
    return (h & 2) ? ((h & 1) ? v.w : v.z) : ((h & 1) ? v.y : v.x);
}
__device__ __forceinline__ float lrelu(float x) { return (x >= 0.f) ? x : 0.2f * x; }

// ======================== setup: deg zero + graph starts ========================
__global__ void init_kernel(int* __restrict__ deg, const int* __restrict__ gid,
                            int* __restrict__ gstart) {
    int i = blockIdx.x * blockDim.x + threadIdx.x;
    if (i < NNODES) deg[i] = 0;
    if (i <= NGRAPH) {
        int lo = 0, hi = NNODES;
        while (lo < hi) {
            int mid = (lo + hi) >> 1;
            if (gid[mid] < i) lo = mid + 1; else hi = mid;
        }
        gstart[i] = lo;
    }
}
__global__ void count_kernel(const int* __restrict__ dst, int* __restrict__ deg) {
    int e = blockIdx.x * blockDim.x + threadIdx.x;
    if (e < NEDGES) atomicAdd(&deg[dst[e]], 1);
}
__global__ __launch_bounds__(1024) void scan_block_kernel(const int* __restrict__ deg,
                                                          int* __restrict__ off,
                                                          int* __restrict__ bsum) {
    __shared__ int buf[1024];
    int t = threadIdx.x;
    int i = blockIdx.x * 1024 + t;
    int x = (i < NNODES) ? deg[i] : 0;
    buf[t] = x;
    __syncthreads();
    for (int s = 1; s < 1024; s <<= 1) {
        int v = (t >= s) ? buf[t - s] : 0;
        __syncthreads();
        buf[t] += v;
        __syncthreads();
    }
    if (i < NNODES) off[i] = buf[t] - x;
    if (t == 1023) bsum[blockIdx.x] = buf[1023];
}
__global__ __launch_bounds__(128) void scan_bsum_kernel(int* __restrict__ bsum) {
    __shared__ int buf[128];
    int t = threadIdx.x;
    int x = (t < NB_SCAN) ? bsum[t] : 0;
    buf[t] = x;
    __syncthreads();
    for (int s = 1; s < 128; s <<= 1) {
        int v = (t >= s) ? buf[t - s] : 0;
        __syncthreads();
        buf[t] += v;
        __syncthreads();
    }
    if (t < NB_SCAN) bsum[t] = buf[t] - x;
    if (t == 0) bsum[NB_SCAN] = buf[NB_SCAN - 1];
}
__global__ __launch_bounds__(1024) void scan_add_kernel(int* __restrict__ off,
                                                        const int* __restrict__ bsum,
                                                        int* __restrict__ cursor) {
    int i = blockIdx.x * 1024 + threadIdx.x;
    if (i < NNODES) {
        int v = off[i] + bsum[blockIdx.x];
        off[i] = v;
        cursor[i] = v;
    }
    if (i == 0) off[NNODES] = bsum[NB_SCAN];
}
__global__ void scatter_kernel(const int* __restrict__ src, const int* __restrict__ dst,
                               int* __restrict__ cursor, int* __restrict__ src_csr) {
    int e = blockIdx.x * blockDim.x + threadIdx.x;
    if (e >= NEDGES) return;
    int p = atomicAdd(&cursor[dst[e]], 1);
    src_csr[p] = src[e];
}

// ======================== combined conversions + gate zero ========================
#define C1 (128 * K1P)
#define C2 (256 * 128)
#define C3 (512 * 256)
#define CG (64 * 512)
#define CX (NNODES * K1P)
#define CTOT (C1 + C2 + C3 + CG + CX + NNODES)
__global__ void conv_all_kernel(const float* __restrict__ W1, const float* __restrict__ W2,
                                const float* __restrict__ W3, const float* __restrict__ Wg1,
                                const float* __restrict__ nf,
                                ushort* __restrict__ Bt1, ushort* __restrict__ Bt2,
                                ushort* __restrict__ Bt3, ushort* __restrict__ Btg,
                                ushort* __restrict__ x0, float* __restrict__ gate) {
    int i = blockIdx.x * blockDim.x + threadIdx.x;
    if (i < C1) {
        int n = i / K1P, k = i - n * K1P;
        Bt1[i] = (k < 92) ? f2bf(W1[(size_t)k * 128 + n]) : (ushort)0;
        return;
    }
    i -= C1;
    if (i < C2) {
        int n = i >> 7, k = i & 127;
        Bt2[i] = f2bf(W2[(size_t)k * 256 + n]);
        return;
    }
    i -= C2;
    if (i < C3) {
        int n = i >> 8, k = i & 255;
        Bt3[i] = f2bf(W3[(size_t)k * 512 + n]);
        return;
    }
    i -= C3;
    if (i < CG) {
        int n = i >> 9, k = i & 511;
        Btg[i] = f2bf(Wg1[(size_t)k * 64 + n]);
        return;
    }
    i -= CG;
    if (i < CX) {
        int n = i / K1P, k = i - n * K1P;
        x0[i] = (k < 92) ? f2bf(nf[(size_t)n * 92 + k]) : (ushort)0;
        return;
    }
    i -= CX;
    if (i < NNODES) gate[i] = 0.f;
}

// ======================== MFMA bf16 GEMM ========================
// grid = (colBlocks, rowBlocks). MODE 0: bf16 C store. MODE 1: fused gate epilogue.
template <int BN, int MODE>
__global__ __launch_bounds__(256) void mfma_gemm(const ushort* __restrict__ A,
                                                 const ushort* __restrict__ Bt,
                                                 const float* __restrict__ bias,
                                                 ushort* __restrict__ C,
                                                 const float* __restrict__ Wg2,
                                                 float* __restrict__ gate,
                                                 int M, int K, int N) {
    constexpr int WNS = BN / 2;
    constexpr int NT = WNS / 16;
    __shared__ ushort Alds[128][40];
    __shared__ ushort Blds[BN][40];
    int tid = threadIdx.x;
    int wave = tid >> 6, lane = tid & 63;
    int wm = wave & 1, wn = wave >> 1;
    int quad = lane >> 4, l16 = lane & 15;
    int rowBase = blockIdx.y * 128;
    int colBase = blockIdx.x * BN;

    f32x4 acc[4][NT];
#pragma unroll
    for (int i = 0; i < 4; i++)
#pragma unroll
        for (int j = 0; j < NT; j++) acc[i][j] = (f32x4){0.f, 0.f, 0.f, 0.f};

    for (int k0 = 0; k0 < K; k0 += 32) {
        {
            int r = tid >> 1;
            int c0 = (tid & 1) * 8;
            int row = rowBase + r;
            uint4 v0 = make_uint4(0u, 0u, 0u, 0u);
            uint4 v1 = make_uint4(0u, 0u, 0u, 0u);
            if (row < M) {
                const ushort* ap = &A[(size_t)row * K + k0];
                v0 = *(const uint4*)&ap[c0];
                v1 = *(const uint4*)&ap[c0 + 16];
            }
            *(uint4*)&Alds[r][c0] = v0;
            *(uint4*)&Alds[r][c0 + 16] = v1;
        }
        if constexpr (BN == 128) {
            int r = tid >> 1;
            int c0 = (tid & 1) * 8;
            const ushort* bp = &Bt[(size_t)(colBase + r) * K + k0];
            *(uint4*)&Blds[r][c0] = *(const uint4*)&bp[c0];
            *(uint4*)&Blds[r][c0 + 16] = *(const uint4*)&bp[c0 + 16];
        } else {
            int r = tid >> 2, ch = tid & 3;
            uint4 v = *(const uint4*)&Bt[(size_t)(colBase + r) * K + k0 + ch * 8];
            *(uint4*)&Blds[r][ch * 8] = v;
        }
        __syncthreads();
        bf16x8 af[4], bf[NT];
#pragma unroll
        for (int i = 0; i < 4; i++)
            af[i] = *(const bf16x8*)&Alds[wm * 64 + i * 16 + l16][quad * 8];
#pragma unroll
        for (int j = 0; j < NT; j++)
            bf[j] = *(const bf16x8*)&Blds[wn * WNS + j * 16 + l16][quad * 8];
#pragma unroll
        for (int i = 0; i < 4; i++)
#pragma unroll
            for (int j = 0; j < NT; j++)
                acc[i][j] = __builtin_amdgcn_mfma_f32_16x16x32_bf16(af[i], bf[j], acc[i][j], 0, 0, 0);
        __syncthreads();
    }

    if constexpr (MODE == 0) {
#pragma unroll
        for (int i = 0; i < 4; i++) {
#pragma unroll
            for (int j = 0; j < NT; j++) {
                int col = colBase + wn * WNS + j * 16 + l16;
#pragma unroll
                for (int r = 0; r < 4; r++) {
                    int row = rowBase + wm * 64 + i * 16 + quad * 4 + r;
                    if (row < M) C[(size_t)row * N + col] = f2bf(acc[i][j][r]);
                }
            }
        }
    } else {
        float bb[NT], wg[NT];
#pragma unroll
        for (int j = 0; j < NT; j++) {
            int col = colBase + wn * WNS + j * 16 + l16;
            bb[j] = bias[col];
            wg[j] = Wg2[col];
        }
#pragma unroll
        for (int i = 0; i < 4; i++) {
            float pd[4] = {0.f, 0.f, 0.f, 0.f};
#pragma unroll
            for (int j = 0; j < NT; j++) {
#pragma unroll
                for (int r = 0; r < 4; r++) {
                    float x = fmaxf(acc[i][j][r] + bb[j], 0.f);
                    pd[r] = fmaf(x, wg[j], pd[r]);
                }
            }
#pragma unroll
            for (int m = 1; m < 16; m <<= 1)
#pragma unroll
                for (int r = 0; r < 4; r++)
                    pd[r] += __shfl_xor(pd[r], m, 64);
            if (l16 == 0) {
#pragma unroll
                for (int r = 0; r < 4; r++) {
                    int row = rowBase + wm * 64 + i * 16 + quad * 4 + r;
                    if (row < M) atomicAdd(&gate[row], pd[r]);
                }
            }
        }
    }
}

// ======================== el/er: wave per node, vectorized ========================
template <int HD>
__global__ __launch_bounds__(256) void eler_node(const ushort* __restrict__ Wh,
                                                 const float* __restrict__ al,
                                                 const float* __restrict__ ar,
                                                 float* __restrict__ el,
                                                 float* __restrict__ er) {
    constexpr int D = HD / NHEAD;
    constexpr int LPN = HD / 8;
    constexpr int S = D / 8;
    int n = blockIdx.x * 4 + (threadIdx.x >> 6);
    int lane = threadIdx.x & 63;
    float sl = 0.f, sr = 0.f;
    if (lane < LPN) {
        int d0 = lane * 8;
        uint4 v = *(const uint4*)&Wh[(size_t)n * HD + d0];
        float w0 = bflo(v.x), w1 = bfhi(v.x), w2 = bflo(v.y), w3 = bfhi(v.y);
        float w4 = bflo(v.z), w5 = bfhi(v.z), w6 = bflo(v.w), w7 = bfhi(v.w);
        float4 a0 = *(const float4*)&al[d0];
        float4 a1 = *(const float4*)&al[d0 + 4];
        float4 b0 = *(const float4*)&ar[d0];
        float4 b1 = *(const float4*)&ar[d0 + 4];
        sl = w0 * a0.x; sl = fmaf(w1, a0.y, sl); sl = fmaf(w2, a0.z, sl); sl = fmaf(w3, a0.w, sl);
        sl = fmaf(w4, a1.x, sl); sl = fmaf(w5, a1.y, sl); sl = fmaf(w6, a1.z, sl); sl = fmaf(w7, a1.w, sl);
        sr = w0 * b0.x; sr = fmaf(w1, b0.y, sr); sr = fmaf(w2, b0.z, sr); sr = fmaf(w3, b0.w, sr);
        sr = fmaf(w4, b1.x, sr); sr = fmaf(w5, b1.y, sr); sr = fmaf(w6, b1.z, sr); sr = fmaf(w7, b1.w, sr);
    }
#pragma unroll
    for (int o = S / 2; o > 0; o >>= 1) {
        sl += __shfl_down(sl, o, 64);
        sr += __shfl_down(sr, o, 64);
    }
    if (lane < LPN && (lane % S) == 0) {
        int h = lane / S;
        el[n * 4 + h] = sl;
        er[n * 4 + h] = sr;
    }
}

// ======================== fused edge-softmax + aggregate (wave per node) ========================
// Phase 1: lanes stripe edges, gather el4[src], online per-head max/sum; butterfly combine.
// Phase 1.5: lane j writes final weight (all 4 heads) for edge i0+j to LDS (j < 64).
// Phase 2: per 8-edge batch, weight via conflict-free LDS broadcast; coalesced Wh gather; FMA.
template <int HD>
__global__ __launch_bounds__(256) void attn_aggregate(const int* __restrict__ src_csr,
                                                      const int* __restrict__ off,
                                                      const ushort* __restrict__ Wh,
                                                      const float4* __restrict__ el4,
                                                      const float4* __restrict__ er4,
                                                      const float* __restrict__ bias,
                                                      ushort* __restrict__ out) {
    constexpr int DPL = HD / 64;  // dims per lane: 8 / 4 / 2
    __shared__ float lds_w[4][SLOTS * 4];  // [node-in-block][slot*4 + head]
    int wi = threadIdx.x >> 6;
    int n = blockIdx.x * 4 + wi;
    int lane = threadIdx.x & 63;
    int i0 = off[n], i1 = off[n + 1];
    int deg = i1 - i0;
    float4 ern = er4[n];

    // ---- phase 1 ----
    float m0 = -1e30f, m1 = -1e30f, m2 = -1e30f, m3 = -1e30f;
    float s0 = 0.f, s1 = 0.f, s2 = 0.f, s3 = 0.f;
    float4 xf = make_float4(0.f, 0.f, 0.f, 0.f);  // first-edge score (lane's slot)
    for (int i = i0 + lane; i < i1; i += 64) {
        float4 x = el4[src_csr[i]];
        x.x = lrelu(x.x + ern.x);
        x.y = lrelu(x.y + ern.y);
        x.z = lrelu(x.z + ern.z);
        x.w = lrelu(x.w + ern.w);
        if (i == i0 + lane) xf = x;
        float M;
        M = fmaxf(m0, x.x); s0 = s0 * expf(m0 - M) + expf(x.x - M); m0 = M;
        M = fmaxf(m1, x.y); s1 = s1 * expf(m1 - M) + expf(x.y - M); m1 = M;
        M = fmaxf(m2, x.z); s2 = s2 * expf(m2 - M) + expf(x.z - M); m2 = M;
        M = fmaxf(m3, x.w); s3 = s3 * expf(m3 - M) + expf(x.w - M); m3 = M;
    }
    float g0 = m0, g1 = m1, g2 = m2, g3 = m3;
#pragma unroll
    for (int o = 1; o < 64; o <<= 1) {
        g0 = fmaxf(g0, __shfl_xor(g0, o, 64));
        g1 = fmaxf(g1, __shfl_xor(g1, o, 64));
        g2 = fmaxf(g2, __shfl_xor(g2, o, 64));
        g3 = fmaxf(g3, __shfl_xor(g3, o, 64));
    }
    s0 *= expf(m0 - g0); s1 *= expf(m1 - g1);
    s2 *= expf(m2 - g2); s3 *= expf(m3 - g3);
#pragma unroll
    for (int o = 1; o < 64; o <<= 1) {
        s0 += __shfl_xor(s0, o, 64);
        s1 += __shfl_xor(s1, o, 64);
        s2 += __shfl_xor(s2, o, 64);
        s3 += __shfl_xor(s3, o, 64);
    }
    float i0v = 1.f / fmaxf(s0, 1e-9f);
    float i1v = 1.f / fmaxf(s1, 1e-9f);
    float i2v = 1.f / fmaxf(s2, 1e-9f);
    float i3v = 1.f / fmaxf(s3, 1e-9f);

    // ---- phase 1.5: park final weights in LDS ----
    if (lane < deg) {  // lane < 64 always; slot = lane
        float* p = &lds_w[wi][lane * 4];
        p[0] = expf(xf.x - g0) * i0v;
        p[1] = expf(xf.y - g1) * i1v;
        p[2] = expf(xf.z - g2) * i2v;
        p[3] = expf(xf.w - g3) * i3v;
    }

    // ---- phase 2: aggregate ----
    int h = lane >> 4;  // head for this lane's dim range (holds for HD=128/256/512)
    int d = lane * DPL;
    float gmh = (h & 2) ? ((h & 1) ? g3 : g2) : ((h & 1) ? g1 : g0);
    float invh = (h & 2) ? ((h & 1) ? i3v : i2v) : ((h & 1) ? i1v : i0v);
    float erh = selh(ern, h);
    float acc[DPL];
#pragma unroll
    for (int j = 0; j < DPL; j++) acc[j] = 0.f;
    for (int i = i0; i < i1; i += 8) {
        int cnt = i1 - i; if (cnt > 8) cnt = 8;
        int s8[8]; float w8[8];
#pragma unroll
        for (int j = 0; j < 8; j++)
            if (j < cnt) s8[j] = src_csr[i + j];
#pragma unroll
        for (int j = 0; j < 8; j++) {
            if (j < cnt) {
                int slot = i + j - i0;
                if (slot < SLOTS) {
                    w8[j] = lds_w[wi][slot * 4 + h];
                } else {  // rare fallback: deg > 64
                    float xs = lrelu(selh(el4[s8[j]], h) + erh);
                    w8[j] = expf(xs - gmh) * invh;
                }
            }
        }
#pragma unroll
        for (int j = 0; j < 8; j++) {
            if (j < cnt) {
                const ushort* p = &Wh[(size_t)s8[j] * HD + d];
                float w = w8[j];
                if constexpr (DPL == 8) {
                    uint4 v = *(const uint4*)p;
                    acc[0] = fmaf(w, bflo(v.x), acc[0]);
                    acc[1] = fmaf(w, bfhi(v.x), acc[1]);
                    acc[2] = fmaf(w, bflo(v.y), acc[2]);
                    acc[3] = fmaf(w, bfhi(v.y), acc[3]);
                    acc[4] = fmaf(w, bflo(v.z), acc[4]);
                    acc[5] = fmaf(w, bfhi(v.z), acc[5]);
                    acc[6] = fmaf(w, bflo(v.w), acc[6]);
                    acc[7] = fmaf(w, bfhi(v.w), acc[7]);
                } else if constexpr (DPL == 4) {
                    uint2 v = *(const uint2*)p;
                    acc[0] = fmaf(w, bflo(v.x), acc[0]);
                    acc[1] = fmaf(w, bfhi(v.x), acc[1]);
                    acc[2] = fmaf(w, bflo(v.y), acc[2]);
                    acc[3] = fmaf(w, bfhi(v.y), acc[3]);
                } else {
                    uint v = *(const uint*)p;
                    acc[0] = fmaf(w, bflo(v), acc[0]);
                    acc[1] = fmaf(w, bfhi(v), acc[1]);
                }
            }
        }
    }
    // epilogue: bias + ELU, pack, store
    float r[DPL];
#pragma unroll
    for (int j = 0; j < DPL; j++) {
        float x = acc[j] + bias[d + j];
        r[j] = (x > 0.f) ? x : (expf(x) - 1.f);
    }
    ushort* po = &out[(size_t)n * HD + d];
    if constexpr (DPL == 8) {
        uint4 o;
        o.x = pack2(r[0], r[1]); o.y = pack2(r[2], r[3]);
        o.z = pack2(r[4], r[5]); o.w = pack2(r[6], r[7]);
        *(uint4*)po = o;
    } else if constexpr (DPL == 4) {
        uint2 o;
        o.x = pack2(r[0], r[1]); o.y = pack2(r[2], r[3]);
        *(uint2*)po = o;
    } else {
        *(uint*)po = pack2(r[0], r[1]);
    }
}

// ======================== per-graph softmax over node gates ========================
__global__ __launch_bounds__(256) void graph_softmax_kernel(const float* __restrict__ gate,
                                                            const int* __restrict__ gstart,
                                                            float* __restrict__ exn,
                                                            float* __restrict__ gsum) {
    int g = blockIdx.x, t = threadIdx.x;
    int n0 = gstart[g], n1 = gstart[g + 1];
    __shared__ float red[256];
    float m = -1e30f;
    for (int n = n0 + t; n < n1; n += 256) m = fmaxf(m, gate[n]);
    red[t] = m; __syncthreads();
    for (int s = 128; s > 0; s >>= 1) {
        if (t < s) red[t] = fmaxf(red[t], red[t + s]);
        __syncthreads();
    }
    m = red[0]; __syncthreads();
    float sum = 0.f;
    for (int n = n0 + t; n < n1; n += 256) {
        float v = expf(gate[n] - m);
        exn[n] = v;
        sum += v;
    }
    red[t] = sum; __syncthreads();
    for (int s = 128; s > 0; s >>= 1) {
        if (t < s) red[t] += red[t + s];
        __syncthreads();
    }
    if (t == 0) gsum[g] = red[0];
}

// ======================== pooled partial sums (PQ blocks per graph) ========================
__global__ __launch_bounds__(128) void pool_partial(const ushort* __restrict__ h,
                                                    const float* __restrict__ exn,
                                                    const int* __restrict__ gstart,
                                                    float* __restrict__ partial) {
    int g = blockIdx.x, q = blockIdx.y;
    int n0 = gstart[g], n1 = gstart[g + 1];
    int len = n1 - n0;
    int chunk = (len + PQ - 1) / PQ;
    int s = n0 + q * chunk;
    int e = s + chunk; if (e > n1) e = n1;
    int d4 = threadIdx.x;
    const uint2* h2 = (const uint2*)h;
    float a0 = 0.f, a1 = 0.f, a2 = 0.f, a3 = 0.f;
    for (int n = s; n < e; n++) {
        float w = exn[n];
        uint2 v = h2[(size_t)n * 128 + d4];
        a0 = fmaf(w, bflo(v.x), a0);
        a1 = fmaf(w, bfhi(v.x), a1);
        a2 = fmaf(w, bflo(v.y), a2);
        a3 = fmaf(w, bfhi(v.y), a3);
    }
    *(float4*)&partial[((size_t)(g * PQ + q)) * FINALD + d4 * 4] = make_float4(a0, a1, a2, a3);
}

// ======================== final heads ========================
__global__ __launch_bounds__(128) void final_kernel(const float* __restrict__ partial,
                                                    const float* __restrict__ gsum,
                                                    const float* __restrict__ Wmu,
                                                    const float* __restrict__ bmu,
                                                    const float* __restrict__ Wlv,
                                                    const float* __restrict__ blv,
                                                    float* __restrict__ out) {
    int g = blockIdx.x, j = threadIdx.x;
    __shared__ float pooled[FINALD];
    const float* p = partial + (size_t)g * PQ * FINALD;
    for (int k = j; k < FINALD; k += 128) {
        float v = 0.f;
#pragma unroll
        for (int q = 0; q < PQ; q++) v += p[q * FINALD + k];
        pooled[k] = v;
    }
    __syncthreads();
    float am = 0.f, av = 0.f;
    for (int k = 0; k < FINALD; k++) {
        float pv = pooled[k];
        am = fmaf(pv, Wmu[k * LATD + j], am);
        av = fmaf(pv, Wlv[k * LATD + j], av);
    }
    float inv = 1.f / fmaxf(gsum[g], 1e-9f);
    out[g * LATD + j] = am * inv + bmu[j];
    out[NGRAPH * LATD + g * LATD + j] = av * inv + blv[j];
}

// ======================== driver ========================
extern "C" void kernel_launch(void* const* d_in, const int* in_sizes, int n_in,
                              void* d_out, int out_size, void* d_ws, size_t ws_size,
                              hipStream_t stream) {
    (void)in_sizes; (void)n_in; (void)out_size; (void)ws_size;
    const float* node_feat = (const float*)d_in[0];
    const int* src = (const int*)d_in[1];
    const int* dst = (const int*)d_in[2];
    const int* gid = (const int*)d_in[3];
    const float* W[3]    = {(const float*)d_in[4],  (const float*)d_in[8],  (const float*)d_in[12]};
    const float* al[3]   = {(const float*)d_in[5],  (const float*)d_in[9],  (const float*)d_in[13]};
    const float* ar[3]   = {(const float*)d_in[6],  (const float*)d_in[10], (const float*)d_in[14]};
    const float* bias[3] = {(const float*)d_in[7],  (const float*)d_in[11], (const float*)d_in[15]};
    const float* Wg1 = (const float*)d_in[16];
    const float* bg1 = (const float*)d_in[17];
    const float* Wg2 = (const float*)d_in[18];
    // bg2 cancels in the node softmax — unused.
    const float* Wmu = (const float*)d_in[20];
    const float* bmu = (const float*)d_in[21];
    const float* Wlv = (const float*)d_in[22];
    const float* blv = (const float*)d_in[23];

    char* ws = (char*)d_ws;
    size_t woff = 0;
    auto carve = [&](size_t bytes) {
        void* p = ws + woff;
        woff = (woff + bytes + 255) & ~(size_t)255;
        return p;
    };
    ushort* hA      = (ushort*)carve((size_t)NNODES * 512 * 2);
    ushort* hB      = (ushort*)carve((size_t)NNODES * 512 * 2);
    float*  el      = (float*) carve((size_t)NNODES * 4 * 4);
    float*  er      = (float*) carve((size_t)NNODES * 4 * 4);
    int*    deg     = (int*)   carve((size_t)NNODES * 4);
    int*    off     = (int*)   carve((size_t)(NNODES + 1) * 4);
    int*    cursor  = (int*)   carve((size_t)NNODES * 4);
    int*    src_csr = (int*)   carve((size_t)NEDGES * 4);
    int*    bsum    = (int*)   carve((size_t)(NB_SCAN + 1) * 4);
    float*  gate    = (float*) carve((size_t)NNODES * 4);
    float*  exn     = (float*) carve((size_t)NNODES * 4);
    int*    gstart  = (int*)   carve((size_t)(NGRAPH + 1) * 4);
    float*  partial = (float*) carve((size_t)NGRAPH * PQ * FINALD * 4);
    float*  gsum    = (float*) carve((size_t)NGRAPH * 4);
    ushort* Bt1     = (ushort*)carve((size_t)128 * K1P * 2);
    ushort* Bt2     = (ushort*)carve((size_t)256 * 128 * 2);
    ushort* Bt3     = (ushort*)carve((size_t)512 * 256 * 2);
    ushort* Btg     = (ushort*)carve((size_t)64 * 512 * 2);
    ushort* x0      = hA;  // alias: x0 dead before hA first written (L1 aggregate)

    // ---- setup (7 launches) ----
    init_kernel<<<(NNODES + 255) / 256, 256, 0, stream>>>(deg, gid, gstart);
    count_kernel<<<(NEDGES + 255) / 256, 256, 0, stream>>>(dst, deg);
    scan_block_kernel<<<NB_SCAN, 1024, 0, stream>>>(deg, off, bsum);
    scan_bsum_kernel<<<1, 128, 0, stream>>>(bsum);
    scan_add_kernel<<<NB_SCAN, 1024, 0, stream>>>(off, bsum, cursor);
    scatter_kernel<<<(NEDGES + 255) / 256, 256, 0, stream>>>(src, dst, cursor, src_csr);
    conv_all_kernel<<<(CTOT + 255) / 256, 256, 0, stream>>>(
        W[0], W[1], W[2], Wg1, node_feat, Bt1, Bt2, Bt3, Btg, x0, gate);

    const int MB = (NNODES + 127) / 128;  // 782
    const int NWB = NNODES / 4;           // 25000 blocks, wave per node

    for (int l = 0; l < 3; l++) {
        if (l == 0) {
            mfma_gemm<128, 0><<<dim3(1, MB), 256, 0, stream>>>(
                x0, Bt1, nullptr, hB, nullptr, nullptr, NNODES, K1P, 128);
            eler_node<128><<<NWB, 256, 0, stream>>>(hB, al[0], ar[0], el, er);
            attn_aggregate<128><<<NWB, 256, 0, stream>>>(
                src_csr, off, hB, (const float4*)el, (const float4*)er, bias[0], hA);
        } else if (l == 1) {
            mfma_gemm<128, 0><<<dim3(2, MB), 256, 0, stream>>>(
                hA, Bt2, nullptr, hB, nullptr, nullptr, NNODES, 128, 256);
            eler_node<256><<<NWB, 256, 0, stream>>>(hB, al[1], ar[1], el, er);
            attn_aggregate<256><<<NWB, 256, 0, stream>>>(
                src_csr, off, hB, (const float4*)el, (const float4*)er, bias[1], hA);
        } else {
            mfma_gemm<128, 0><<<dim3(4, MB), 256, 0, stream>>>(
                hA, Bt3, nullptr, hB, nullptr, nullptr, NNODES, 256, 512);
            eler_node<512><<<NWB, 256, 0, stream>>>(hB, al[2], ar[2], el, er);
            attn_aggregate<512><<<NWB, 256, 0, stream>>>(
                src_csr, off, hB, (const float4*)el, (const float4*)er, bias[2], hA);
        }
    }

    // ---- attention pooling + heads (4 launches) ----
    mfma_gemm<64, 1><<<dim3(1, MB), 256, 0, stream>>>(
        hA, Btg, bg1, nullptr, Wg2, gate, NNODES, FINALD, HIDG);
    graph_softmax_kernel<<<NGRAPH, 256, 0, stream>>>(gate, gstart, exn, gsum);
    pool_partial<<<dim3(NGRAPH, PQ), 128, 0, stream>>>(hA, exn, gstart, partial);
    final_kernel<<<NGRAPH, 128, 0, stream>>>(partial, gsum, Wmu, bmu, Wlv, blv, (float*)d_out);
}

// Round 13
// 777.318 us; speedup vs baseline: 1.0770x; 1.0770x over previous
//
#include <hip/hip_runtime.h>
#include <math.h>

#define NNODES 100000
#define NEDGES 800000
#define NGRAPH 64
#define NHEAD  4
#define FINALD 512
#define HIDG   64
#define LATD   128
#define K1P    96   // layer-1 K padded (92 -> 96)
#define NB_SCAN 98  // ceil(NNODES/1024)
#define PQ     16   // pool chunks per graph

typedef unsigned int uint;
typedef unsigned short ushort;
typedef __attribute__((ext_vector_type(8))) short bf16x8;
typedef __attribute__((ext_vector_type(4))) float f32x4;

// ---- bf16 helpers ----
__device__ __forceinline__ float bflo(uint u) { return __uint_as_float(u << 16); }
__device__ __forceinline__ float bfhi(uint u) { return __uint_as_float(u & 0xffff0000u); }
__device__ __forceinline__ ushort f2bf(float f) {
    uint u = __float_as_uint(f);
    return (ushort)((u + 0x7fffu + ((u >> 16) & 1u)) >> 16);
}
__device__ __forceinline__ uint pack2(float a, float b) {
    return (uint)f2bf(a) | ((uint)f2bf(b) << 16);
}

// ======================== setup: deg zero + graph starts ========================
__global__ void init_kernel(int* __restrict__ deg, const int* __restrict__ gid,
                            int* __restrict__ gstart) {
    int i = blockIdx.x * blockDim.x + threadIdx.x;
    if (i < NNODES) deg[i] = 0;
    if (i <= NGRAPH) {
        int lo = 0, hi = NNODES;
        while (lo < hi) {
            int mid = (lo + hi) >> 1;
            if (gid[mid] < i) lo = mid + 1; else hi = mid;
        }
        gstart[i] = lo;
    }
}
__global__ void count_kernel(const int* __restrict__ dst, int* __restrict__ deg) {
    int e = blockIdx.x * blockDim.x + threadIdx.x;
    if (e < NEDGES) atomicAdd(&deg[dst[e]], 1);
}
__global__ __launch_bounds__(1024) void scan_block_kernel(const int* __restrict__ deg,
                                                          int* __restrict__ off,
                                                          int* __restrict__ bsum) {
    __shared__ int buf[1024];
    int t = threadIdx.x;
    int i = blockIdx.x * 1024 + t;
    int x = (i < NNODES) ? deg[i] : 0;
    buf[t] = x;
    __syncthreads();
    for (int s = 1; s < 1024; s <<= 1) {
        int v = (t >= s) ? buf[t - s] : 0;
        __syncthreads();
        buf[t] += v;
        __syncthreads();
    }
    if (i < NNODES) off[i] = buf[t] - x;
    if (t == 1023) bsum[blockIdx.x] = buf[1023];
}
__global__ __launch_bounds__(128) void scan_bsum_kernel(int* __restrict__ bsum) {
    __shared__ int buf[128];
    int t = threadIdx.x;
    int x = (t < NB_SCAN) ? bsum[t] : 0;
    buf[t] = x;
    __syncthreads();
    for (int s = 1; s < 128; s <<= 1) {
        int v = (t >= s) ? buf[t - s] : 0;
        __syncthreads();
        buf[t] += v;
        __syncthreads();
    }
    if (t < NB_SCAN) bsum[t] = buf[t] - x;
    if (t == 0) bsum[NB_SCAN] = buf[NB_SCAN - 1];
}
__global__ __launch_bounds__(1024) void scan_add_kernel(int* __restrict__ off,
                                                        const int* __restrict__ bsum,
                                                        int* __restrict__ cursor) {
    int i = blockIdx.x * 1024 + threadIdx.x;
    if (i < NNODES) {
        int v = off[i] + bsum[blockIdx.x];
        off[i] = v;
        cursor[i] = v;
    }
    if (i == 0) off[NNODES] = bsum[NB_SCAN];
}
__global__ void scatter_kernel(const int* __restrict__ src, const int* __restrict__ dst,
                               int* __restrict__ cursor, int* __restrict__ src_csr) {
    int e = blockIdx.x * blockDim.x + threadIdx.x;
    if (e >= NEDGES) return;
    int p = atomicAdd(&cursor[dst[e]], 1);
    src_csr[p] = src[e];
}

// ======================== combined conversions + gate zero ========================
#define C1 (128 * K1P)
#define C2 (256 * 128)
#define C3 (512 * 256)
#define CG (64 * 512)
#define CX (NNODES * K1P)
#define CTOT (C1 + C2 + C3 + CG + CX + NNODES)
__global__ void conv_all_kernel(const float* __restrict__ W1, const float* __restrict__ W2,
                                const float* __restrict__ W3, const float* __restrict__ Wg1,
                                const float* __restrict__ nf,
                                ushort* __restrict__ Bt1, ushort* __restrict__ Bt2,
                                ushort* __restrict__ Bt3, ushort* __restrict__ Btg,
                                ushort* __restrict__ x0, float* __restrict__ gate) {
    int i = blockIdx.x * blockDim.x + threadIdx.x;
    if (i < C1) {
        int n = i / K1P, k = i - n * K1P;
        Bt1[i] = (k < 92) ? f2bf(W1[(size_t)k * 128 + n]) : (ushort)0;
        return;
    }
    i -= C1;
    if (i < C2) {
        int n = i >> 7, k = i & 127;
        Bt2[i] = f2bf(W2[(size_t)k * 256 + n]);
        return;
    }
    i -= C2;
    if (i < C3) {
        int n = i >> 8, k = i & 255;
        Bt3[i] = f2bf(W3[(size_t)k * 512 + n]);
        return;
    }
    i -= C3;
    if (i < CG) {
        int n = i >> 9, k = i & 511;
        Btg[i] = f2bf(Wg1[(size_t)k * 64 + n]);
        return;
    }
    i -= CG;
    if (i < CX) {
        int n = i / K1P, k = i - n * K1P;
        x0[i] = (k < 92) ? f2bf(nf[(size_t)n * 92 + k]) : (ushort)0;
        return;
    }
    i -= CX;
    if (i < NNODES) gate[i] = 0.f;
}

// ======================== MFMA bf16 GEMM ========================
// grid = (colBlocks, rowBlocks). MODE 0: bf16 C store. MODE 1: fused gate epilogue.
template <int BN, int MODE>
__global__ __launch_bounds__(256) void mfma_gemm(const ushort* __restrict__ A,
                                                 const ushort* __restrict__ Bt,
                                                 const float* __restrict__ bias,
                                                 ushort* __restrict__ C,
                                                 const float* __restrict__ Wg2,
                                                 float* __restrict__ gate,
                                                 int M, int K, int N) {
    constexpr int WNS = BN / 2;
    constexpr int NT = WNS / 16;
    __shared__ ushort Alds[128][40];
    __shared__ ushort Blds[BN][40];
    int tid = threadIdx.x;
    int wave = tid >> 6, lane = tid & 63;
    int wm = wave & 1, wn = wave >> 1;
    int quad = lane >> 4, l16 = lane & 15;
    int rowBase = blockIdx.y * 128;
    int colBase = blockIdx.x * BN;

    f32x4 acc[4][NT];
#pragma unroll
    for (int i = 0; i < 4; i++)
#pragma unroll
        for (int j = 0; j < NT; j++) acc[i][j] = (f32x4){0.f, 0.f, 0.f, 0.f};

    for (int k0 = 0; k0 < K; k0 += 32) {
        {
            int r = tid >> 1;
            int c0 = (tid & 1) * 8;
            int row = rowBase + r;
            uint4 v0 = make_uint4(0u, 0u, 0u, 0u);
            uint4 v1 = make_uint4(0u, 0u, 0u, 0u);
            if (row < M) {
                const ushort* ap = &A[(size_t)row * K + k0];
                v0 = *(const uint4*)&ap[c0];
                v1 = *(const uint4*)&ap[c0 + 16];
            }
            *(uint4*)&Alds[r][c0] = v0;
            *(uint4*)&Alds[r][c0 + 16] = v1;
        }
        if constexpr (BN == 128) {
            int r = tid >> 1;
            int c0 = (tid & 1) * 8;
            const ushort* bp = &Bt[(size_t)(colBase + r) * K + k0];
            *(uint4*)&Blds[r][c0] = *(const uint4*)&bp[c0];
            *(uint4*)&Blds[r][c0 + 16] = *(const uint4*)&bp[c0 + 16];
        } else {
            int r = tid >> 2, ch = tid & 3;
            uint4 v = *(const uint4*)&Bt[(size_t)(colBase + r) * K + k0 + ch * 8];
            *(uint4*)&Blds[r][ch * 8] = v;
        }
        __syncthreads();
        bf16x8 af[4], bf[NT];
#pragma unroll
        for (int i = 0; i < 4; i++)
            af[i] = *(const bf16x8*)&Alds[wm * 64 + i * 16 + l16][quad * 8];
#pragma unroll
        for (int j = 0; j < NT; j++)
            bf[j] = *(const bf16x8*)&Blds[wn * WNS + j * 16 + l16][quad * 8];
#pragma unroll
        for (int i = 0; i < 4; i++)
#pragma unroll
            for (int j = 0; j < NT; j++)
                acc[i][j] = __builtin_amdgcn_mfma_f32_16x16x32_bf16(af[i], bf[j], acc[i][j], 0, 0, 0);
        __syncthreads();
    }

    if constexpr (MODE == 0) {
#pragma unroll
        for (int i = 0; i < 4; i++) {
#pragma unroll
            for (int j = 0; j < NT; j++) {
                int col = colBase + wn * WNS + j * 16 + l16;
#pragma unroll
                for (int r = 0; r < 4; r++) {
                    int row = rowBase + wm * 64 + i * 16 + quad * 4 + r;
                    if (row < M) C[(size_t)row * N + col] = f2bf(acc[i][j][r]);
                }
            }
        }
    } else {
        float bb[NT], wg[NT];
#pragma unroll
        for (int j = 0; j < NT; j++) {
            int col = colBase + wn * WNS + j * 16 + l16;
            bb[j] = bias[col];
            wg[j] = Wg2[col];
        }
#pragma unroll
        for (int i = 0; i < 4; i++) {
            float pd[4] = {0.f, 0.f, 0.f, 0.f};
#pragma unroll
            for (int j = 0; j < NT; j++) {
#pragma unroll
                for (int r = 0; r < 4; r++) {
                    float x = fmaxf(acc[i][j][r] + bb[j], 0.f);
                    pd[r] = fmaf(x, wg[j], pd[r]);
                }
            }
#pragma unroll
            for (int m = 1; m < 16; m <<= 1)
#pragma unroll
                for (int r = 0; r < 4; r++)
                    pd[r] += __shfl_xor(pd[r], m, 64);
            if (l16 == 0) {
#pragma unroll
                for (int r = 0; r < 4; r++) {
                    int row = rowBase + wm * 64 + i * 16 + quad * 4 + r;
                    if (row < M) atomicAdd(&gate[row], pd[r]);
                }
            }
        }
    }
}

// ======================== el/er: multi-node-per-wave, vectorized ========================
// LPN = lanes per node (HD/8); NPW = nodes per wave (64/LPN). All 64 lanes active.
template <int HD>
__global__ __launch_bounds__(256) void eler_node(const ushort* __restrict__ Wh,
                                                 const float* __restrict__ al,
                                                 const float* __restrict__ ar,
                                                 float* __restrict__ el,
                                                 float* __restrict__ er) {
    constexpr int LPN = HD / 8;
    constexpr int NPW = 64 / LPN;
    constexpr int S = (HD / NHEAD) / 8;  // lanes per head
    int wave = threadIdx.x >> 6;
    int lane = threadIdx.x & 63;
    int sub = lane & (LPN - 1);
    int n = blockIdx.x * (4 * NPW) + wave * NPW + lane / LPN;
    int d0 = sub * 8;
    uint4 v = *(const uint4*)&Wh[(size_t)n * HD + d0];
    float w0 = bflo(v.x), w1 = bfhi(v.x), w2 = bflo(v.y), w3 = bfhi(v.y);
    float w4 = bflo(v.z), w5 = bfhi(v.z), w6 = bflo(v.w), w7 = bfhi(v.w);
    float4 a0 = *(const float4*)&al[d0];
    float4 a1 = *(const float4*)&al[d0 + 4];
    float4 b0 = *(const float4*)&ar[d0];
    float4 b1 = *(const float4*)&ar[d0 + 4];
    float sl, sr;
    sl = w0 * a0.x; sl = fmaf(w1, a0.y, sl); sl = fmaf(w2, a0.z, sl); sl = fmaf(w3, a0.w, sl);
    sl = fmaf(w4, a1.x, sl); sl = fmaf(w5, a1.y, sl); sl = fmaf(w6, a1.z, sl); sl = fmaf(w7, a1.w, sl);
    sr = w0 * b0.x; sr = fmaf(w1, b0.y, sr); sr = fmaf(w2, b0.z, sr); sr = fmaf(w3, b0.w, sr);
    sr = fmaf(w4, b1.x, sr); sr = fmaf(w5, b1.y, sr); sr = fmaf(w6, b1.z, sr); sr = fmaf(w7, b1.w, sr);
#pragma unroll
    for (int o = S / 2; o > 0; o >>= 1) {
        sl += __shfl_down(sl, o, 64);
        sr += __shfl_down(sr, o, 64);
    }
    if ((sub & (S - 1)) == 0) {
        int h = sub / S;
        el[n * 4 + h] = sl;
        er[n * 4 + h] = sr;
    }
}

// ======================== per-node edge softmax (unnormalized; sum out) ========================
__global__ void attn_node(const int* __restrict__ src_csr, const int* __restrict__ off,
                          const float4* __restrict__ el4, const float4* __restrict__ er4,
                          float4* __restrict__ aw4, float4* __restrict__ nsum4) {
    int n = blockIdx.x * blockDim.x + threadIdx.x;
    if (n >= NNODES) return;
    int i0 = off[n], i1 = off[n + 1];
    float4 ern = er4[n];
    float m0 = -1e30f, m1 = -1e30f, m2 = -1e30f, m3 = -1e30f;
    for (int i = i0; i < i1; i += 8) {
        int cnt = i1 - i; if (cnt > 8) cnt = 8;
        int s8[8];
#pragma unroll
        for (int j = 0; j < 8; j++)
            if (j < cnt) s8[j] = src_csr[i + j];
        float4 e8[8];
#pragma unroll
        for (int j = 0; j < 8; j++)
            if (j < cnt) e8[j] = el4[s8[j]];
#pragma unroll
        for (int j = 0; j < 8; j++) {
            if (j < cnt) {
                float4 x = e8[j];
                x.x += ern.x; x.y += ern.y; x.z += ern.z; x.w += ern.w;
                x.x = (x.x >= 0.f) ? x.x : 0.2f * x.x;
                x.y = (x.y >= 0.f) ? x.y : 0.2f * x.y;
                x.z = (x.z >= 0.f) ? x.z : 0.2f * x.z;
                x.w = (x.w >= 0.f) ? x.w : 0.2f * x.w;
                aw4[i + j] = x;
                m0 = fmaxf(m0, x.x); m1 = fmaxf(m1, x.y);
                m2 = fmaxf(m2, x.z); m3 = fmaxf(m3, x.w);
            }
        }
    }
    float4 s = make_float4(0.f, 0.f, 0.f, 0.f);
    for (int i = i0; i < i1; i++) {
        float4 x = aw4[i];
        x.x = expf(x.x - m0); x.y = expf(x.y - m1);
        x.z = expf(x.z - m2); x.w = expf(x.w - m3);
        s.x += x.x; s.y += x.y; s.z += x.z; s.w += x.w;
        aw4[i] = x;
    }
    nsum4[n] = s;
}

// ======================== aggregate: 8 bf16 dims/thread, 8-edge batch ========================
__global__ __launch_bounds__(256) void gat_aggregate(const int* __restrict__ src_csr,
                                                     const int* __restrict__ off,
                                                     const ushort* __restrict__ Wh,
                                                     const float* __restrict__ aw,
                                                     const float* __restrict__ nsum,
                                                     const float* __restrict__ bias,
                                                     ushort* __restrict__ out,
                                                     int HD, int logHD8, int logD, int total8) {
    int idx = blockIdx.x * blockDim.x + threadIdx.x;
    if (idx >= total8) return;
    int n = idx >> logHD8;
    int d = (idx & ((1 << logHD8) - 1)) << 3;
    int h = d >> logD;
    int i0 = off[n], i1 = off[n + 1];
    float acc[8] = {0.f, 0.f, 0.f, 0.f, 0.f, 0.f, 0.f, 0.f};
    for (int i = i0; i < i1; i += 8) {
        int cnt = i1 - i; if (cnt > 8) cnt = 8;
        int s8[8]; float w8[8];
#pragma unroll
        for (int j = 0; j < 8; j++) {
            if (j < cnt) {
                s8[j] = src_csr[i + j];
                w8[j] = aw[(i + j) * 4 + h];
            }
        }
#pragma unroll
        for (int j = 0; j < 8; j++) {
            if (j < cnt) {
                uint4 v = *(const uint4*)&Wh[(size_t)s8[j] * HD + d];
                float w = w8[j];
                acc[0] = fmaf(w, bflo(v.x), acc[0]);
                acc[1] = fmaf(w, bfhi(v.x), acc[1]);
                acc[2] = fmaf(w, bflo(v.y), acc[2]);
                acc[3] = fmaf(w, bfhi(v.y), acc[3]);
                acc[4] = fmaf(w, bflo(v.z), acc[4]);
                acc[5] = fmaf(w, bfhi(v.z), acc[5]);
                acc[6] = fmaf(w, bflo(v.w), acc[6]);
                acc[7] = fmaf(w, bfhi(v.w), acc[7]);
            }
        }
    }
    float inv = 1.f / fmaxf(nsum[n * 4 + h], 1e-9f);
    float r[8];
#pragma unroll
    for (int j = 0; j < 8; j++) {
        float x = acc[j] * inv + bias[d + j];
        r[j] = (x > 0.f) ? x : (expf(x) - 1.f);
    }
    uint4 o;
    o.x = pack2(r[0], r[1]);
    o.y = pack2(r[2], r[3]);
    o.z = pack2(r[4], r[5]);
    o.w = pack2(r[6], r[7]);
    *(uint4*)&out[(size_t)n * HD + d] = o;
}

// ======================== per-graph softmax over node gates ========================
__global__ __launch_bounds__(256) void graph_softmax_kernel(const float* __restrict__ gate,
                                                            const int* __restrict__ gstart,
                                                            float* __restrict__ exn,
                                                            float* __restrict__ gsum) {
    int g = blockIdx.x, t = threadIdx.x;
    int n0 = gstart[g], n1 = gstart[g + 1];
    __shared__ float red[256];
    float m = -1e30f;
    for (int n = n0 + t; n < n1; n += 256) m = fmaxf(m, gate[n]);
    red[t] = m; __syncthreads();
    for (int s = 128; s > 0; s >>= 1) {
        if (t < s) red[t] = fmaxf(red[t], red[t + s]);
        __syncthreads();
    }
    m = red[0]; __syncthreads();
    float sum = 0.f;
    for (int n = n0 + t; n < n1; n += 256) {
        float v = expf(gate[n] - m);
        exn[n] = v;
        sum += v;
    }
    red[t] = sum; __syncthreads();
    for (int s = 128; s > 0; s >>= 1) {
        if (t < s) red[t] += red[t + s];
        __syncthreads();
    }
    if (t == 0) gsum[g] = red[0];
}

// ======================== pooled partial sums (PQ blocks per graph) ========================
__global__ __launch_bounds__(128) void pool_partial(const ushort* __restrict__ h,
                                                    const float* __restrict__ exn,
                                                    const int* __restrict__ gstart,
                                                    float* __restrict__ partial) {
    int g = blockIdx.x, q = blockIdx.y;
    int n0 = gstart[g], n1 = gstart[g + 1];
    int len = n1 - n0;
    int chunk = (len + PQ - 1) / PQ;
    int s = n0 + q * chunk;
    int e = s + chunk; if (e > n1) e = n1;
    int d4 = threadIdx.x;
    const uint2* h2 = (const uint2*)h;
    float a0 = 0.f, a1 = 0.f, a2 = 0.f, a3 = 0.f;
    for (int n = s; n < e; n++) {
        float w = exn[n];
        uint2 v = h2[(size_t)n * 128 + d4];
        a0 = fmaf(w, bflo(v.x), a0);
        a1 = fmaf(w, bfhi(v.x), a1);
        a2 = fmaf(w, bflo(v.y), a2);
        a3 = fmaf(w, bfhi(v.y), a3);
    }
    *(float4*)&partial[((size_t)(g * PQ + q)) * FINALD + d4 * 4] = make_float4(a0, a1, a2, a3);
}

// ======================== final heads ========================
__global__ __launch_bounds__(128) void final_kernel(const float* __restrict__ partial,
                                                    const float* __restrict__ gsum,
                                                    const float* __restrict__ Wmu,
                                                    const float* __restrict__ bmu,
                                                    const float* __restrict__ Wlv,
                                                    const float* __restrict__ blv,
                                                    float* __restrict__ out) {
    int g = blockIdx.x, j = threadIdx.x;
    __shared__ float pooled[FINALD];
    const float* p = partial + (size_t)g * PQ * FINALD;
    for (int k = j; k < FINALD; k += 128) {
        float v = 0.f;
#pragma unroll
        for (int q = 0; q < PQ; q++) v += p[q * FINALD + k];
        pooled[k] = v;
    }
    __syncthreads();
    float am = 0.f, av = 0.f;
    for (int k = 0; k < FINALD; k++) {
        float pv = pooled[k];
        am = fmaf(pv, Wmu[k * LATD + j], am);
        av = fmaf(pv, Wlv[k * LATD + j], av);
    }
    float inv = 1.f / fmaxf(gsum[g], 1e-9f);
    out[g * LATD + j] = am * inv + bmu[j];
    out[NGRAPH * LATD + g * LATD + j] = av * inv + blv[j];
}

// ======================== driver ========================
extern "C" void kernel_launch(void* const* d_in, const int* in_sizes, int n_in,
                              void* d_out, int out_size, void* d_ws, size_t ws_size,
                              hipStream_t stream) {
    (void)in_sizes; (void)n_in; (void)out_size; (void)ws_size;
    const float* node_feat = (const float*)d_in[0];
    const int* src = (const int*)d_in[1];
    const int* dst = (const int*)d_in[2];
    const int* gid = (const int*)d_in[3];
    const float* W[3]    = {(const float*)d_in[4],  (const float*)d_in[8],  (const float*)d_in[12]};
    const float* al[3]   = {(const float*)d_in[5],  (const float*)d_in[9],  (const float*)d_in[13]};
    const float* ar[3]   = {(const float*)d_in[6],  (const float*)d_in[10], (const float*)d_in[14]};
    const float* bias[3] = {(const float*)d_in[7],  (const float*)d_in[11], (const float*)d_in[15]};
    const float* Wg1 = (const float*)d_in[16];
    const float* bg1 = (const float*)d_in[17];
    const float* Wg2 = (const float*)d_in[18];
    // bg2 cancels in the node softmax — unused.
    const float* Wmu = (const float*)d_in[20];
    const float* bmu = (const float*)d_in[21];
    const float* Wlv = (const float*)d_in[22];
    const float* blv = (const float*)d_in[23];

    char* ws = (char*)d_ws;
    size_t woff = 0;
    auto carve = [&](size_t bytes) {
        void* p = ws + woff;
        woff = (woff + bytes + 255) & ~(size_t)255;
        return p;
    };
    ushort* hA      = (ushort*)carve((size_t)NNODES * 512 * 2);
    ushort* hB      = (ushort*)carve((size_t)NNODES * 512 * 2);
    float*  el      = (float*) carve((size_t)NNODES * 4 * 4);
    float*  er      = (float*) carve((size_t)NNODES * 4 * 4);
    float*  aw      = (float*) carve((size_t)NEDGES * 4 * 4);
    float*  nsum    = (float*) carve((size_t)NNODES * 4 * 4);
    int*    deg     = (int*)   carve((size_t)NNODES * 4);
    int*    off     = (int*)   carve((size_t)(NNODES + 1) * 4);
    int*    cursor  = (int*)   carve((size_t)NNODES * 4);
    int*    src_csr = (int*)   carve((size_t)NEDGES * 4);
    int*    bsum    = (int*)   carve((size_t)(NB_SCAN + 1) * 4);
    float*  gate    = (float*) carve((size_t)NNODES * 4);
    float*  exn     = (float*) carve((size_t)NNODES * 4);
    int*    gstart  = (int*)   carve((size_t)(NGRAPH + 1) * 4);
    float*  partial = (float*) carve((size_t)NGRAPH * PQ * FINALD * 4);
    float*  gsum    = (float*) carve((size_t)NGRAPH * 4);
    ushort* Bt1     = (ushort*)carve((size_t)128 * K1P * 2);
    ushort* Bt2     = (ushort*)carve((size_t)256 * 128 * 2);
    ushort* Bt3     = (ushort*)carve((size_t)512 * 256 * 2);
    ushort* Btg     = (ushort*)carve((size_t)64 * 512 * 2);
    ushort* x0      = hA;  // alias: x0 dead before hA first written (L1 aggregate)

    // ---- setup (7 launches) ----
    init_kernel<<<(NNODES + 255) / 256, 256, 0, stream>>>(deg, gid, gstart);
    count_kernel<<<(NEDGES + 255) / 256, 256, 0, stream>>>(dst, deg);
    scan_block_kernel<<<NB_SCAN, 1024, 0, stream>>>(deg, off, bsum);
    scan_bsum_kernel<<<1, 128, 0, stream>>>(bsum);
    scan_add_kernel<<<NB_SCAN, 1024, 0, stream>>>(off, bsum, cursor);
    scatter_kernel<<<(NEDGES + 255) / 256, 256, 0, stream>>>(src, dst, cursor, src_csr);
    conv_all_kernel<<<(CTOT + 255) / 256, 256, 0, stream>>>(
        W[0], W[1], W[2], Wg1, node_feat, Bt1, Bt2, Bt3, Btg, x0, gate);

    const int HDs[3]    = {128, 256, 512};
    const int logHD8[3] = {4, 5, 6};
    const int logD[3]   = {5, 6, 7};
    const int MB = (NNODES + 127) / 128;  // 782

    for (int l = 0; l < 3; l++) {
        int HD = HDs[l];
        if (l == 0)
            mfma_gemm<128, 0><<<dim3(1, MB), 256, 0, stream>>>(
                x0, Bt1, nullptr, hB, nullptr, nullptr, NNODES, K1P, 128);
        else if (l == 1)
            mfma_gemm<128, 0><<<dim3(2, MB), 256, 0, stream>>>(
                hA, Bt2, nullptr, hB, nullptr, nullptr, NNODES, 128, 256);
        else
            mfma_gemm<128, 0><<<dim3(4, MB), 256, 0, stream>>>(
                hA, Bt3, nullptr, hB, nullptr, nullptr, NNODES, 256, 512);
        // eler: 4*NPW nodes per block; NNODES divisible by 16/8/4 for all layers
        if (l == 0)      eler_node<128><<<NNODES / 16, 256, 0, stream>>>(hB, al[l], ar[l], el, er);
        else if (l == 1) eler_node<256><<<NNODES / 8, 256, 0, stream>>>(hB, al[l], ar[l], el, er);
        else             eler_node<512><<<NNODES / 4, 256, 0, stream>>>(hB, al[l], ar[l], el, er);
        attn_node<<<(NNODES + 255) / 256, 256, 0, stream>>>(
            src_csr, off, (const float4*)el, (const float4*)er, (float4*)aw, (float4*)nsum);
        int total8 = NNODES * (HD / 8);
        gat_aggregate<<<(total8 + 255) / 256, 256, 0, stream>>>(
            src_csr, off, hB, aw, nsum, bias[l], hA, HD, logHD8[l], logD[l], total8);
    }

    // ---- attention pooling + heads (4 launches) ----
    mfma_gemm<64, 1><<<dim3(1, MB), 256, 0, stream>>>(
        hA, Btg, bg1, nullptr, Wg2, gate, NNODES, FINALD, HIDG);
    graph_softmax_kernel<<<NGRAPH, 256, 0, stream>>>(gate, gstart, exn, gsum);
    pool_partial<<<dim3(NGRAPH, PQ), 128, 0, stream>>>(hA, exn, gstart, partial);
    final_kernel<<<NGRAPH, 128, 0, stream>>>(partial, gsum, Wmu, bmu, Wlv, blv, (float*)d_out);
}

// Round 14
// 773.335 us; speedup vs baseline: 1.0826x; 1.0052x over previous
//
#include <hip/hip_runtime.h>
#include <math.h>

#define NNODES 100000
#define NEDGES 800000
#define NGRAPH 64
#define NHEAD  4
#define FINALD 512
#define HIDG   64
#define LATD   128
#define K1P    96   // layer-1 K padded (92 -> 96)
#define NB_SCAN 98  // ceil(NNODES/1024)
#define PQ     16   // pool chunks per graph

typedef unsigned int uint;
typedef unsigned short ushort;
typedef __attribute__((ext_vector_type(8))) short bf16x8;
typedef __attribute__((ext_vector_type(4))) float f32x4;

// ---- bf16 helpers ----
__device__ __forceinline__ float bflo(uint u) { return __uint_as_float(u << 16); }
__device__ __forceinline__ float bfhi(uint u) { return __uint_as_float(u & 0xffff0000u); }
__device__ __forceinline__ ushort f2bf(float f) {
    uint u = __float_as_uint(f);
    return (ushort)((u + 0x7fffu + ((u >> 16) & 1u)) >> 16);
}
__device__ __forceinline__ uint pack2(float a, float b) {
    return (uint)f2bf(a) | ((uint)f2bf(b) << 16);
}

// ---- async global->LDS, 16B per lane, wave-uniform LDS base ----
__device__ __forceinline__ void async_copy16(const ushort* gsrc, ushort* lds_base) {
    __builtin_amdgcn_global_load_lds(
        (const __attribute__((address_space(1))) uint*)gsrc,
        (__attribute__((address_space(3))) uint*)lds_base,
        16, 0, 0);
}

// ======================== setup: deg zero + graph starts ========================
__global__ void init_kernel(int* __restrict__ deg, const int* __restrict__ gid,
                            int* __restrict__ gstart) {
    int i = blockIdx.x * blockDim.x + threadIdx.x;
    if (i < NNODES) deg[i] = 0;
    if (i <= NGRAPH) {
        int lo = 0, hi = NNODES;
        while (lo < hi) {
            int mid = (lo + hi) >> 1;
            if (gid[mid] < i) lo = mid + 1; else hi = mid;
        }
        gstart[i] = lo;
    }
}
__global__ void count_kernel(const int* __restrict__ dst, int* __restrict__ deg) {
    int e = blockIdx.x * blockDim.x + threadIdx.x;
    if (e < NEDGES) atomicAdd(&deg[dst[e]], 1);
}
__global__ __launch_bounds__(1024) void scan_block_kernel(const int* __restrict__ deg,
                                                          int* __restrict__ off,
                                                          int* __restrict__ bsum) {
    __shared__ int buf[1024];
    int t = threadIdx.x;
    int i = blockIdx.x * 1024 + t;
    int x = (i < NNODES) ? deg[i] : 0;
    buf[t] = x;
    __syncthreads();
    for (int s = 1; s < 1024; s <<= 1) {
        int v = (t >= s) ? buf[t - s] : 0;
        __syncthreads();
        buf[t] += v;
        __syncthreads();
    }
    if (i < NNODES) off[i] = buf[t] - x;
    if (t == 1023) bsum[blockIdx.x] = buf[1023];
}
__global__ __launch_bounds__(128) void scan_bsum_kernel(int* __restrict__ bsum) {
    __shared__ int buf[128];
    int t = threadIdx.x;
    int x = (t < NB_SCAN) ? bsum[t] : 0;
    buf[t] = x;
    __syncthreads();
    for (int s = 1; s < 128; s <<= 1) {
        int v = (t >= s) ? buf[t - s] : 0;
        __syncthreads();
        buf[t] += v;
        __syncthreads();
    }
    if (t < NB_SCAN) bsum[t] = buf[t] - x;
    if (t == 0) bsum[NB_SCAN] = buf[NB_SCAN - 1];
}
__global__ __launch_bounds__(1024) void scan_add_kernel(int* __restrict__ off,
                                                        const int* __restrict__ bsum,
                                                        int* __restrict__ cursor) {
    int i = blockIdx.x * 1024 + threadIdx.x;
    if (i < NNODES) {
        int v = off[i] + bsum[blockIdx.x];
        off[i] = v;
        cursor[i] = v;
    }
    if (i == 0) off[NNODES] = bsum[NB_SCAN];
}
__global__ void scatter_kernel(const int* __restrict__ src, const int* __restrict__ dst,
                               int* __restrict__ cursor, int* __restrict__ src_csr) {
    int e = blockIdx.x * blockDim.x + threadIdx.x;
    if (e >= NEDGES) return;
    int p = atomicAdd(&cursor[dst[e]], 1);
    src_csr[p] = src[e];
}

// ======================== combined conversions + gate zero ========================
#define C1 (128 * K1P)
#define C2 (256 * 128)
#define C3 (512 * 256)
#define CG (64 * 512)
#define CX (NNODES * K1P)
#define CTOT (C1 + C2 + C3 + CG + CX + NNODES)
__global__ void conv_all_kernel(const float* __restrict__ W1, const float* __restrict__ W2,
                                const float* __restrict__ W3, const float* __restrict__ Wg1,
                                const float* __restrict__ nf,
                                ushort* __restrict__ Bt1, ushort* __restrict__ Bt2,
                                ushort* __restrict__ Bt3, ushort* __restrict__ Btg,
                                ushort* __restrict__ x0, float* __restrict__ gate) {
    int i = blockIdx.x * blockDim.x + threadIdx.x;
    if (i < C1) {
        int n = i / K1P, k = i - n * K1P;
        Bt1[i] = (k < 92) ? f2bf(W1[(size_t)k * 128 + n]) : (ushort)0;
        return;
    }
    i -= C1;
    if (i < C2) {
        int n = i >> 7, k = i & 127;
        Bt2[i] = f2bf(W2[(size_t)k * 256 + n]);
        return;
    }
    i -= C2;
    if (i < C3) {
        int n = i >> 8, k = i & 255;
        Bt3[i] = f2bf(W3[(size_t)k * 512 + n]);
        return;
    }
    i -= C3;
    if (i < CG) {
        int n = i >> 9, k = i & 511;
        Btg[i] = f2bf(Wg1[(size_t)k * 64 + n]);
        return;
    }
    i -= CG;
    if (i < CX) {
        int n = i / K1P, k = i - n * K1P;
        x0[i] = (k < 92) ? f2bf(nf[(size_t)n * 92 + k]) : (ushort)0;
        return;
    }
    i -= CX;
    if (i < NNODES) gate[i] = 0.f;
}

// ======================== MFMA bf16 GEMM (async global_load_lds staging) ========================
// grid = (colBlocks, rowBlocks). MODE 0: bf16 C store. MODE 1: fused gate epilogue.
// LDS tiles UNPADDED [rows][32] (64B rows) — required by global_load_lds lane mapping.
// OOB A rows (row >= M) read garbage from adjacent ws buffers; their outputs are masked.
template <int BN, int MODE>
__global__ __launch_bounds__(256) void mfma_gemm(const ushort* __restrict__ A,
                                                 const ushort* __restrict__ Bt,
                                                 const float* __restrict__ bias,
                                                 ushort* __restrict__ C,
                                                 const float* __restrict__ Wg2,
                                                 float* __restrict__ gate,
                                                 int M, int K, int N) {
    constexpr int WNS = BN / 2;
    constexpr int NT = WNS / 16;
    __shared__ ushort Alds[128][32];
    __shared__ ushort Blds[BN][32];
    int tid = threadIdx.x;
    int wave = tid >> 6, lane = tid & 63;
    int wm = wave & 1, wn = wave >> 1;
    int quad = lane >> 4, l16 = lane & 15;
    int rowBase = blockIdx.y * 128;
    int colBase = blockIdx.x * BN;

    // per-lane source geometry for 16-row chunks: lane -> (row l>>2, 16B piece l&3)
    int srow = lane >> 2;
    int scol = (lane & 3) * 8;  // ushort offset of the 16B piece

    f32x4 acc[4][NT];
#pragma unroll
    for (int i = 0; i < 4; i++)
#pragma unroll
        for (int j = 0; j < NT; j++) acc[i][j] = (f32x4){0.f, 0.f, 0.f, 0.f};

    for (int k0 = 0; k0 < K; k0 += 32) {
        // stage A: 128 rows x 64B = 8 chunks; wave w handles chunks 2w, 2w+1
#pragma unroll
        for (int c = 0; c < 2; c++) {
            int chunk = wave * 2 + c;
            int row = rowBase + chunk * 16 + srow;
            async_copy16(&A[(size_t)row * K + k0 + scol], &Alds[chunk * 16][0]);
        }
        // stage B
        if constexpr (BN == 128) {
#pragma unroll
            for (int c = 0; c < 2; c++) {
                int chunk = wave * 2 + c;
                int row = colBase + chunk * 16 + srow;
                async_copy16(&Bt[(size_t)row * K + k0 + scol], &Blds[chunk * 16][0]);
            }
        } else {  // BN == 64: 4 chunks, one per wave
            int row = colBase + wave * 16 + srow;
            async_copy16(&Bt[(size_t)row * K + k0 + scol], &Blds[wave * 16][0]);
        }
        __syncthreads();
        bf16x8 af[4], bf[NT];
#pragma unroll
        for (int i = 0; i < 4; i++)
            af[i] = *(const bf16x8*)&Alds[wm * 64 + i * 16 + l16][quad * 8];
#pragma unroll
        for (int j = 0; j < NT; j++)
            bf[j] = *(const bf16x8*)&Blds[wn * WNS + j * 16 + l16][quad * 8];
#pragma unroll
        for (int i = 0; i < 4; i++)
#pragma unroll
            for (int j = 0; j < NT; j++)
                acc[i][j] = __builtin_amdgcn_mfma_f32_16x16x32_bf16(af[i], bf[j], acc[i][j], 0, 0, 0);
        __syncthreads();
    }

    if constexpr (MODE == 0) {
#pragma unroll
        for (int i = 0; i < 4; i++) {
#pragma unroll
            for (int j = 0; j < NT; j++) {
                int col = colBase + wn * WNS + j * 16 + l16;
#pragma unroll
                for (int r = 0; r < 4; r++) {
                    int row = rowBase + wm * 64 + i * 16 + quad * 4 + r;
                    if (row < M) C[(size_t)row * N + col] = f2bf(acc[i][j][r]);
                }
            }
        }
    } else {
        float bb[NT], wg[NT];
#pragma unroll
        for (int j = 0; j < NT; j++) {
            int col = colBase + wn * WNS + j * 16 + l16;
            bb[j] = bias[col];
            wg[j] = Wg2[col];
        }
#pragma unroll
        for (int i = 0; i < 4; i++) {
            float pd[4] = {0.f, 0.f, 0.f, 0.f};
#pragma unroll
            for (int j = 0; j < NT; j++) {
#pragma unroll
                for (int r = 0; r < 4; r++) {
                    float x = fmaxf(acc[i][j][r] + bb[j], 0.f);
                    pd[r] = fmaf(x, wg[j], pd[r]);
                }
            }
#pragma unroll
            for (int m = 1; m < 16; m <<= 1)
#pragma unroll
                for (int r = 0; r < 4; r++)
                    pd[r] += __shfl_xor(pd[r], m, 64);
            if (l16 == 0) {
#pragma unroll
                for (int r = 0; r < 4; r++) {
                    int row = rowBase + wm * 64 + i * 16 + quad * 4 + r;
                    if (row < M) atomicAdd(&gate[row], pd[r]);
                }
            }
        }
    }
}

// ======================== el/er: multi-node-per-wave, vectorized ========================
template <int HD>
__global__ __launch_bounds__(256) void eler_node(const ushort* __restrict__ Wh,
                                                 const float* __restrict__ al,
                                                 const float* __restrict__ ar,
                                                 float* __restrict__ el,
                                                 float* __restrict__ er) {
    constexpr int LPN = HD / 8;
    constexpr int NPW = 64 / LPN;
    constexpr int S = (HD / NHEAD) / 8;
    int wave = threadIdx.x >> 6;
    int lane = threadIdx.x & 63;
    int sub = lane & (LPN - 1);
    int n = blockIdx.x * (4 * NPW) + wave * NPW + lane / LPN;
    int d0 = sub * 8;
    uint4 v = *(const uint4*)&Wh[(size_t)n * HD + d0];
    float w0 = bflo(v.x), w1 = bfhi(v.x), w2 = bflo(v.y), w3 = bfhi(v.y);
    float w4 = bflo(v.z), w5 = bfhi(v.z), w6 = bflo(v.w), w7 = bfhi(v.w);
    float4 a0 = *(const float4*)&al[d0];
    float4 a1 = *(const float4*)&al[d0 + 4];
    float4 b0 = *(const float4*)&ar[d0];
    float4 b1 = *(const float4*)&ar[d0 + 4];
    float sl, sr;
    sl = w0 * a0.x; sl = fmaf(w1, a0.y, sl); sl = fmaf(w2, a0.z, sl); sl = fmaf(w3, a0.w, sl);
    sl = fmaf(w4, a1.x, sl); sl = fmaf(w5, a1.y, sl); sl = fmaf(w6, a1.z, sl); sl = fmaf(w7, a1.w, sl);
    sr = w0 * b0.x; sr = fmaf(w1, b0.y, sr); sr = fmaf(w2, b0.z, sr); sr = fmaf(w3, b0.w, sr);
    sr = fmaf(w4, b1.x, sr); sr = fmaf(w5, b1.y, sr); sr = fmaf(w6, b1.z, sr); sr = fmaf(w7, b1.w, sr);
#pragma unroll
    for (int o = S / 2; o > 0; o >>= 1) {
        sl += __shfl_down(sl, o, 64);
        sr += __shfl_down(sr, o, 64);
    }
    if ((sub & (S - 1)) == 0) {
        int h = sub / S;
        el[n * 4 + h] = sl;
        er[n * 4 + h] = sr;
    }
}

// ======================== per-node edge softmax (unnormalized; sum out) ========================
__global__ void attn_node(const int* __restrict__ src_csr, const int* __restrict__ off,
                          const float4* __restrict__ el4, const float4* __restrict__ er4,
                          float4* __restrict__ aw4, float4* __restrict__ nsum4) {
    int n = blockIdx.x * blockDim.x + threadIdx.x;
    if (n >= NNODES) return;
    int i0 = off[n], i1 = off[n + 1];
    float4 ern = er4[n];
    float m0 = -1e30f, m1 = -1e30f, m2 = -1e30f, m3 = -1e30f;
    for (int i = i0; i < i1; i += 8) {
        int cnt = i1 - i; if (cnt > 8) cnt = 8;
        int s8[8];
#pragma unroll
        for (int j = 0; j < 8; j++)
            if (j < cnt) s8[j] = src_csr[i + j];
        float4 e8[8];
#pragma unroll
        for (int j = 0; j < 8; j++)
            if (j < cnt) e8[j] = el4[s8[j]];
#pragma unroll
        for (int j = 0; j < 8; j++) {
            if (j < cnt) {
                float4 x = e8[j];
                x.x += ern.x; x.y += ern.y; x.z += ern.z; x.w += ern.w;
                x.x = (x.x >= 0.f) ? x.x : 0.2f * x.x;
                x.y = (x.y >= 0.f) ? x.y : 0.2f * x.y;
                x.z = (x.z >= 0.f) ? x.z : 0.2f * x.z;
                x.w = (x.w >= 0.f) ? x.w : 0.2f * x.w;
                aw4[i + j] = x;
                m0 = fmaxf(m0, x.x); m1 = fmaxf(m1, x.y);
                m2 = fmaxf(m2, x.z); m3 = fmaxf(m3, x.w);
            }
        }
    }
    float4 s = make_float4(0.f, 0.f, 0.f, 0.f);
    for (int i = i0; i < i1; i++) {
        float4 x = aw4[i];
        x.x = expf(x.x - m0); x.y = expf(x.y - m1);
        x.z = expf(x.z - m2); x.w = expf(x.w - m3);
        s.x += x.x; s.y += x.y; s.z += x.z; s.w += x.w;
        aw4[i] = x;
    }
    nsum4[n] = s;
}

// ======================== aggregate: 8 bf16 dims/thread, 8-edge batch ========================
__global__ __launch_bounds__(256) void gat_aggregate(const int* __restrict__ src_csr,
                                                     const int* __restrict__ off,
                                                     const ushort* __restrict__ Wh,
                                                     const float* __restrict__ aw,
                                                     const float* __restrict__ nsum,
                                                     const float* __restrict__ bias,
                                                     ushort* __restrict__ out,
                                                     int HD, int logHD8, int logD, int total8) {
    int idx = blockIdx.x * blockDim.x + threadIdx.x;
    if (idx >= total8) return;
    int n = idx >> logHD8;
    int d = (idx & ((1 << logHD8) - 1)) << 3;
    int h = d >> logD;
    int i0 = off[n], i1 = off[n + 1];
    float acc[8] = {0.f, 0.f, 0.f, 0.f, 0.f, 0.f, 0.f, 0.f};
    for (int i = i0; i < i1; i += 8) {
        int cnt = i1 - i; if (cnt > 8) cnt = 8;
        int s8[8]; float w8[8];
#pragma unroll
        for (int j = 0; j < 8; j++) {
            if (j < cnt) {
                s8[j] = src_csr[i + j];
                w8[j] = aw[(i + j) * 4 + h];
            }
        }
#pragma unroll
        for (int j = 0; j < 8; j++) {
            if (j < cnt) {
                uint4 v = *(const uint4*)&Wh[(size_t)s8[j] * HD + d];
                float w = w8[j];
                acc[0] = fmaf(w, bflo(v.x), acc[0]);
                acc[1] = fmaf(w, bfhi(v.x), acc[1]);
                acc[2] = fmaf(w, bflo(v.y), acc[2]);
                acc[3] = fmaf(w, bfhi(v.y), acc[3]);
                acc[4] = fmaf(w, bflo(v.z), acc[4]);
                acc[5] = fmaf(w, bfhi(v.z), acc[5]);
                acc[6] = fmaf(w, bflo(v.w), acc[6]);
                acc[7] = fmaf(w, bfhi(v.w), acc[7]);
            }
        }
    }
    float inv = 1.f / fmaxf(nsum[n * 4 + h], 1e-9f);
    float r[8];
#pragma unroll
    for (int j = 0; j < 8; j++) {
        float x = acc[j] * inv + bias[d + j];
        r[j] = (x > 0.f) ? x : (expf(x) - 1.f);
    }
    uint4 o;
    o.x = pack2(r[0], r[1]);
    o.y = pack2(r[2], r[3]);
    o.z = pack2(r[4], r[5]);
    o.w = pack2(r[6], r[7]);
    *(uint4*)&out[(size_t)n * HD + d] = o;
}

// ======================== per-graph softmax over node gates ========================
__global__ __launch_bounds__(256) void graph_softmax_kernel(const float* __restrict__ gate,
                                                            const int* __restrict__ gstart,
                                                            float* __restrict__ exn,
                                                            float* __restrict__ gsum) {
    int g = blockIdx.x, t = threadIdx.x;
    int n0 = gstart[g], n1 = gstart[g + 1];
    __shared__ float red[256];
    float m = -1e30f;
    for (int n = n0 + t; n < n1; n += 256) m = fmaxf(m, gate[n]);
    red[t] = m; __syncthreads();
    for (int s = 128; s > 0; s >>= 1) {
        if (t < s) red[t] = fmaxf(red[t], red[t + s]);
        __syncthreads();
    }
    m = red[0]; __syncthreads();
    float sum = 0.f;
    for (int n = n0 + t; n < n1; n += 256) {
        float v = expf(gate[n] - m);
        exn[n] = v;
        sum += v;
    }
    red[t] = sum; __syncthreads();
    for (int s = 128; s > 0; s >>= 1) {
        if (t < s) red[t] += red[t + s];
        __syncthreads();
    }
    if (t == 0) gsum[g] = red[0];
}

// ======================== pooled partial sums (PQ blocks per graph) ========================
__global__ __launch_bounds__(128) void pool_partial(const ushort* __restrict__ h,
                                                    const float* __restrict__ exn,
                                                    const int* __restrict__ gstart,
                                                    float* __restrict__ partial) {
    int g = blockIdx.x, q = blockIdx.y;
    int n0 = gstart[g], n1 = gstart[g + 1];
    int len = n1 - n0;
    int chunk = (len + PQ - 1) / PQ;
    int s = n0 + q * chunk;
    int e = s + chunk; if (e > n1) e = n1;
    int d4 = threadIdx.x;
    const uint2* h2 = (const uint2*)h;
    float a0 = 0.f, a1 = 0.f, a2 = 0.f, a3 = 0.f;
    for (int n = s; n < e; n++) {
        float w = exn[n];
        uint2 v = h2[(size_t)n * 128 + d4];
        a0 = fmaf(w, bflo(v.x), a0);
        a1 = fmaf(w, bfhi(v.x), a1);
        a2 = fmaf(w, bflo(v.y), a2);
        a3 = fmaf(w, bfhi(v.y), a3);
    }
    *(float4*)&partial[((size_t)(g * PQ + q)) * FINALD + d4 * 4] = make_float4(a0, a1, a2, a3);
}

// ======================== final heads ========================
__global__ __launch_bounds__(128) void final_kernel(const float* __restrict__ partial,
                                                    const float* __restrict__ gsum,
                                                    const float* __restrict__ Wmu,
                                                    const float* __restrict__ bmu,
                                                    const float* __restrict__ Wlv,
                                                    const float* __restrict__ blv,
                                                    float* __restrict__ out) {
    int g = blockIdx.x, j = threadIdx.x;
    __shared__ float pooled[FINALD];
    const float* p = partial + (size_t)g * PQ * FINALD;
    for (int k = j; k < FINALD; k += 128) {
        float v = 0.f;
#pragma unroll
        for (int q = 0; q < PQ; q++) v += p[q * FINALD + k];
        pooled[k] = v;
    }
    __syncthreads();
    float am = 0.f, av = 0.f;
    for (int k = 0; k < FINALD; k++) {
        float pv = pooled[k];
        am = fmaf(pv, Wmu[k * LATD + j], am);
        av = fmaf(pv, Wlv[k * LATD + j], av);
    }
    float inv = 1.f / fmaxf(gsum[g], 1e-9f);
    out[g * LATD + j] = am * inv + bmu[j];
    out[NGRAPH * LATD + g * LATD + j] = av * inv + blv[j];
}

// ======================== driver ========================
extern "C" void kernel_launch(void* const* d_in, const int* in_sizes, int n_in,
                              void* d_out, int out_size, void* d_ws, size_t ws_size,
                              hipStream_t stream) {
    (void)in_sizes; (void)n_in; (void)out_size; (void)ws_size;
    const float* node_feat = (const float*)d_in[0];
    const int* src = (const int*)d_in[1];
    const int* dst = (const int*)d_in[2];
    const int* gid = (const int*)d_in[3];
    const float* W[3]    = {(const float*)d_in[4],  (const float*)d_in[8],  (const float*)d_in[12]};
    const float* al[3]   = {(const float*)d_in[5],  (const float*)d_in[9],  (const float*)d_in[13]};
    const float* ar[3]   = {(const float*)d_in[6],  (const float*)d_in[10], (const float*)d_in[14]};
    const float* bias[3] = {(const float*)d_in[7],  (const float*)d_in[11], (const float*)d_in[15]};
    const float* Wg1 = (const float*)d_in[16];
    const float* bg1 = (const float*)d_in[17];
    const float* Wg2 = (const float*)d_in[18];
    // bg2 cancels in the node softmax — unused.
    const float* Wmu = (const float*)d_in[20];
    const float* bmu = (const float*)d_in[21];
    const float* Wlv = (const float*)d_in[22];
    const float* blv = (const float*)d_in[23];

    char* ws = (char*)d_ws;
    size_t woff = 0;
    auto carve = [&](size_t bytes) {
        void* p = ws + woff;
        woff = (woff + bytes + 255) & ~(size_t)255;
        return p;
    };
    ushort* hA      = (ushort*)carve((size_t)NNODES * 512 * 2);
    ushort* hB      = (ushort*)carve((size_t)NNODES * 512 * 2);
    float*  el      = (float*) carve((size_t)NNODES * 4 * 4);
    float*  er      = (float*) carve((size_t)NNODES * 4 * 4);
    float*  aw      = (float*) carve((size_t)NEDGES * 4 * 4);
    float*  nsum    = (float*) carve((size_t)NNODES * 4 * 4);
    int*    deg     = (int*)   carve((size_t)NNODES * 4);
    int*    off     = (int*)   carve((size_t)(NNODES + 1) * 4);
    int*    cursor  = (int*)   carve((size_t)NNODES * 4);
    int*    src_csr = (int*)   carve((size_t)NEDGES * 4);
    int*    bsum    = (int*)   carve((size_t)(NB_SCAN + 1) * 4);
    float*  gate    = (float*) carve((size_t)NNODES * 4);
    float*  exn     = (float*) carve((size_t)NNODES * 4);
    int*    gstart  = (int*)   carve((size_t)(NGRAPH + 1) * 4);
    float*  partial = (float*) carve((size_t)NGRAPH * PQ * FINALD * 4);
    float*  gsum    = (float*) carve((size_t)NGRAPH * 4);
    ushort* Bt1     = (ushort*)carve((size_t)128 * K1P * 2);
    ushort* Bt2     = (ushort*)carve((size_t)256 * 128 * 2);
    ushort* Bt3     = (ushort*)carve((size_t)512 * 256 * 2);
    ushort* Btg     = (ushort*)carve((size_t)64 * 512 * 2 + 4096);  // +4KB guard for async OOB reads
    ushort* x0      = hA;  // alias: x0 dead before hA first written (L1 aggregate)

    // ---- setup (7 launches) ----
    init_kernel<<<(NNODES + 255) / 256, 256, 0, stream>>>(deg, gid, gstart);
    count_kernel<<<(NEDGES + 255) / 256, 256, 0, stream>>>(dst, deg);
    scan_block_kernel<<<NB_SCAN, 1024, 0, stream>>>(deg, off, bsum);
    scan_bsum_kernel<<<1, 128, 0, stream>>>(bsum);
    scan_add_kernel<<<NB_SCAN, 1024, 0, stream>>>(off, bsum, cursor);
    scatter_kernel<<<(NEDGES + 255) / 256, 256, 0, stream>>>(src, dst, cursor, src_csr);
    conv_all_kernel<<<(CTOT + 255) / 256, 256, 0, stream>>>(
        W[0], W[1], W[2], Wg1, node_feat, Bt1, Bt2, Bt3, Btg, x0, gate);

    const int HDs[3]    = {128, 256, 512};
    const int logHD8[3] = {4, 5, 6};
    const int logD[3]   = {5, 6, 7};
    const int MB = (NNODES + 127) / 128;  // 782

    for (int l = 0; l < 3; l++) {
        int HD = HDs[l];
        if (l == 0)
            mfma_gemm<128, 0><<<dim3(1, MB), 256, 0, stream>>>(
                x0, Bt1, nullptr, hB, nullptr, nullptr, NNODES, K1P, 128);
        else if (l == 1)
            mfma_gemm<128, 0><<<dim3(2, MB), 256, 0, stream>>>(
                hA, Bt2, nullptr, hB, nullptr, nullptr, NNODES, 128, 256);
        else
            mfma_gemm<128, 0><<<dim3(4, MB), 256, 0, stream>>>(
                hA, Bt3, nullptr, hB, nullptr, nullptr, NNODES, 256, 512);
        if (l == 0)      eler_node<128><<<NNODES / 16, 256, 0, stream>>>(hB, al[l], ar[l], el, er);
        else if (l == 1) eler_node<256><<<NNODES / 8, 256, 0, stream>>>(hB, al[l], ar[l], el, er);
        else             eler_node<512><<<NNODES / 4, 256, 0, stream>>>(hB, al[l], ar[l], el, er);
        attn_node<<<(NNODES + 255) / 256, 256, 0, stream>>>(
            src_csr, off, (const float4*)el, (const float4*)er, (float4*)aw, (float4*)nsum);
        int total8 = NNODES * (HD / 8);
        gat_aggregate<<<(total8 + 255) / 256, 256, 0, stream>>>(
            src_csr, off, hB, aw, nsum, bias[l], hA, HD, logHD8[l], logD[l], total8);
    }

    // ---- attention pooling + heads (4 launches) ----
    mfma_gemm<64, 1><<<dim3(1, MB), 256, 0, stream>>>(
        hA, Btg, bg1, nullptr, Wg2, gate, NNODES, FINALD, HIDG);
    graph_softmax_kernel<<<NGRAPH, 256, 0, stream>>>(gate, gstart, exn, gsum);
    pool_partial<<<dim3(NGRAPH, PQ), 128, 0, stream>>>(hA, exn, gstart, partial);
    final_kernel<<<NGRAPH, 128, 0, stream>>>(partial, gsum, Wmu, bmu, Wlv, blv, (float*)d_out);
}